// Round 9
// baseline (173.927 us; speedup 1.0000x reference)
//
#include <hip/hip_runtime.h>
#include <hip/hip_bf16.h>

#define NPTS 131072
#define K 27
#define CIN 64
#define COUT 128
#define BM 64                 // rows per conv block

constexpr float BN_EPS = 1e-5f;
constexpr float NEG_SLOPE = 0.01f;

typedef __attribute__((ext_vector_type(8))) short short8;
typedef __attribute__((ext_vector_type(4))) float f32x4;

typedef const __attribute__((address_space(1))) unsigned int gas_u32;
typedef __attribute__((address_space(3))) unsigned int las_u32;

__device__ inline unsigned int pk_bf16(float a, float b) {
    __hip_bfloat16 ha = __float2bfloat16(a), hb = __float2bfloat16(b);
    unsigned short ua = *reinterpret_cast<unsigned short*>(&ha);
    unsigned short ub = *reinterpret_cast<unsigned short*>(&hb);
    return (unsigned int)ua | ((unsigned int)ub << 16);
}

// ---------------------------------------------------------------------------
// prep_w: W [27][64][128] f32 -> Wt [27][128][64] bf16
// ---------------------------------------------------------------------------
__global__ __launch_bounds__(256) void prep_w(
    const float* __restrict__ W, unsigned short* __restrict__ Wt)
{
    int o = blockIdx.x * 256 + threadIdx.x;           // 221184
    if (o >= K * COUT * CIN) return;
    int k  = o / (COUT * CIN);
    int r  = o % (COUT * CIN);
    int co = r / CIN;
    int ci = r % CIN;
    __hip_bfloat16 h = __float2bfloat16(W[(k * CIN + ci) * COUT + co]);
    Wt[o] = *reinterpret_cast<unsigned short*>(&h);
}

// ---------------------------------------------------------------------------
// prep_f: feats f32 -> bf16 table, (NPTS+1) x 128 B rows (row NPTS = zeros)
// ---------------------------------------------------------------------------
__global__ __launch_bounds__(256) void prep_f(
    const float* __restrict__ feats, unsigned short* __restrict__ featsb)
{
    size_t t = (size_t)blockIdx.x * 256 + threadIdx.x;   // 1,048,576
    const float4* src = (const float4*)(feats) + t * 2;
    float4 v0 = src[0], v1 = src[1];
    uint4 o;
    o.x = pk_bf16(v0.x, v0.y); o.y = pk_bf16(v0.z, v0.w);
    o.z = pk_bf16(v1.x, v1.y); o.w = pk_bf16(v1.z, v1.w);
    ((uint4*)featsb)[t] = o;
}

// ---------------------------------------------------------------------------
// prep_idx: fold mask into index (masked-off -> sentinel zero row NPTS)
// ---------------------------------------------------------------------------
__global__ __launch_bounds__(256) void prep_idx(
    const int* __restrict__ nidx, const int* __restrict__ nmask,
    int* __restrict__ midx)
{
    int t = blockIdx.x * 256 + threadIdx.x;              // 3,538,944
    if (t < NPTS * K) midx[t] = nmask[t] ? nidx[t] : NPTS;
}

// ---------------------------------------------------------------------------
// conv: global_load_lds gather-conv.  256 thr = 4 waves (2x2), 64x128 tile.
// A and B staged DIRECTLY global->LDS (no VGPR round-trip): per-lane global
// source is pre-XOR-swizzled (soff) so the LDS contents match the verified
// XOR-swizzled MFMA read pattern (rule #21 both-sides).  A,B double-buffered:
// ONE barrier + ONE vmcnt(0) per k; loads for k+1 fly across all of MFMA k.
// ---------------------------------------------------------------------------
template<bool MIDX>
__global__ __launch_bounds__(256) void conv_kernel(
    const unsigned short* __restrict__ featsb,   // (NPTS+1) x 64 bf16 rows
    const int* __restrict__ midx,                // if MIDX
    const int* __restrict__ nidx,                // else
    const int* __restrict__ nmask,
    const unsigned short* __restrict__ Wt,       // [27][128][64] bf16
    float* __restrict__ y,
    float* __restrict__ accum)                   // [256]: sums then sumsqs
{
    __shared__ unsigned char Abuf[2][BM * 128];      // 2 x 8 KB
    __shared__ unsigned char Bbuf[2][COUT * 128];    // 2 x 16 KB  (48 KB total)

    const int tid  = threadIdx.x;
    const int l    = tid & 63;
    const int w    = tid >> 6;        // wave 0..3
    const int wr   = w >> 1;          // 0..1 (32 rows)
    const int wc   = w & 1;           // 0..1 (64 cols)
    const int base = blockIdx.x * BM;

    const int lx = l & 7, ly = l >> 3;
    const int soff = (lx ^ ly) << 4;  // pre-swizzle of the global source
    const unsigned char* fb = (const unsigned char*)featsb;   // 128 B rows
    const unsigned char* wb = (const unsigned char*)Wt;       // 128 B rows

    // gather index: A-chunk e (e=0,1) of this wave covers rows (2w+e)*8+ly
    auto ldi = [&](int kq, int e) -> int {
        kq = kq < K ? kq : K - 1;     // clamp (redundant load, never issued)
        int o = (base + (2 * w + e) * 8 + ly) * K + kq;
        if constexpr (MIDX) return midx[o];
        else                return nmask[o] ? nidx[o] : NPTS;
    };

#define ISSUE(BUF, kq, i0, i1)                                                \
    { __builtin_amdgcn_global_load_lds(                                       \
          (gas_u32*)(fb + (size_t)(i0) * 128 + soff),                         \
          (las_u32*)(&Abuf[BUF][(2 * w + 0) * 1024]), 16, 0, 0);              \
      __builtin_amdgcn_global_load_lds(                                       \
          (gas_u32*)(fb + (size_t)(i1) * 128 + soff),                         \
          (las_u32*)(&Abuf[BUF][(2 * w + 1) * 1024]), 16, 0, 0);              \
      _Pragma("unroll")                                                       \
      for (int e = 0; e < 4; ++e)                                             \
          __builtin_amdgcn_global_load_lds(                                   \
              (gas_u32*)(wb + (size_t)(kq) * 16384 + (4 * w + e) * 1024       \
                         + ly * 128 + soff),                                  \
              (las_u32*)(&Bbuf[BUF][(4 * w + e) * 1024]), 16, 0, 0);          \
    }

    f32x4 acc[2][4];
#pragma unroll
    for (int m = 0; m < 2; ++m)
#pragma unroll
        for (int n = 0; n < 4; ++n) acc[m][n] = (f32x4)0.f;

#define MFMA_TILE(BUF)                                                        \
    _Pragma("unroll")                                                         \
    for (int ks = 0; ks < 2; ++ks) {                                          \
        const int kbyte = ks * 64 + (l >> 4) * 16;                            \
        short8 afr[2], bfr[4];                                                \
        _Pragma("unroll")                                                     \
        for (int m = 0; m < 2; ++m) {                                         \
            int row = wr * 32 + m * 16 + (l & 15);                            \
            afr[m] = *(const short8*)(&Abuf[BUF][row * 128                    \
                        + (kbyte ^ ((row & 7) << 4))]);                       \
        }                                                                     \
        _Pragma("unroll")                                                     \
        for (int n = 0; n < 4; ++n) {                                         \
            int col = wc * 64 + n * 16 + (l & 15);                            \
            bfr[n] = *(const short8*)(&Bbuf[BUF][col * 128                    \
                        + (kbyte ^ ((col & 7) << 4))]);                       \
        }                                                                     \
        _Pragma("unroll")                                                     \
        for (int m = 0; m < 2; ++m)                                           \
            _Pragma("unroll")                                                 \
            for (int n = 0; n < 4; ++n)                                       \
                acc[m][n] = __builtin_amdgcn_mfma_f32_16x16x32_bf16(          \
                    afr[m], bfr[n], acc[m][n], 0, 0, 0);                      \
    }

    int id0, id1;                     // gather rows for the NEXT issue

    // ---- prologue: stage k=0, prefetch ids for k=1 ----
    {
        int i0 = ldi(0, 0), i1 = ldi(0, 1);
        ISSUE(0, 0, i0, i1);
        id0 = ldi(1, 0); id1 = ldi(1, 1);
        asm volatile("s_waitcnt vmcnt(0)" ::: "memory");
        __syncthreads();
    }

    // ---- main loop: one barrier per k ----
    for (int q = 0; q < K; ++q) {
        if (q + 1 < K) ISSUE((q + 1) & 1, q + 1, id0, id1);
        id0 = ldi(q + 2, 0); id1 = ldi(q + 2, 1);
        MFMA_TILE(q & 1);
        asm volatile("s_waitcnt vmcnt(0)" ::: "memory");
        __syncthreads();
    }

    // ---- y write (nontemporal: don't evict gather table from L2) ----
#pragma unroll
    for (int m = 0; m < 2; ++m)
#pragma unroll
        for (int n = 0; n < 4; ++n) {
            int gcol = wc * 64 + n * 16 + (l & 15);
#pragma unroll
            for (int r = 0; r < 4; ++r) {
                int grow = base + wr * 32 + m * 16 + (l >> 4) * 4 + r;
                __builtin_nontemporal_store(acc[m][n][r],
                                            &y[(size_t)grow * COUT + gcol]);
            }
        }

    // ---- fused per-block BN stats (reuse Abuf[0] as combine buffer) ----
    float sv[4], s2v[4];
#pragma unroll
    for (int n = 0; n < 4; ++n) {
        float s = 0.f, s2 = 0.f;
#pragma unroll
        for (int m = 0; m < 2; ++m)
#pragma unroll
            for (int r = 0; r < 4; ++r) { float v = acc[m][n][r]; s += v; s2 += v * v; }
        s  += __shfl_xor(s, 16);  s  += __shfl_xor(s, 32);
        s2 += __shfl_xor(s2, 16); s2 += __shfl_xor(s2, 32);
        sv[n] = s; s2v[n] = s2;
    }
    __syncthreads();
    float* statf = (float*)Abuf[0];   // [2][2][128] = 4 KB
    if (l < 16) {
#pragma unroll
        for (int n = 0; n < 4; ++n) {
            int c = wc * 64 + n * 16 + l;
            statf[(0 * 2 + wr) * 128 + c] = sv[n];
            statf[(1 * 2 + wr) * 128 + c] = s2v[n];
        }
    }
    __syncthreads();
    if (tid < 128) {
        atomicAdd(&accum[tid],       statf[0 * 128 + tid] + statf[1 * 128 + tid]);
        atomicAdd(&accum[128 + tid], statf[2 * 128 + tid] + statf[3 * 128 + tid]);
    }
#undef ISSUE
#undef MFMA_TILE
}

// ---------------------------------------------------------------------------
// finalize: fold mean/var/gamma/beta into per-channel scale+bias
// ---------------------------------------------------------------------------
__global__ void finalize_kernel(const float* __restrict__ accum,
                                const float* __restrict__ gamma,
                                const float* __restrict__ beta,
                                float* __restrict__ sb)
{
    int c = threadIdx.x;                      // 128 threads
    float invN  = 1.0f / (float)NPTS;
    float mean  = accum[c] * invN;
    float var   = accum[128 + c] * invN - mean * mean;
    float scale = gamma[c] * rsqrtf(var + BN_EPS);
    sb[c]       = scale;
    sb[128 + c] = beta[c] - mean * scale;
}

// ---------------------------------------------------------------------------
// bn: y = leaky(y*scale+bias), float4-vectorized, scale/bias in registers
// ---------------------------------------------------------------------------
__global__ __launch_bounds__(256) void bn_kernel(
    float* __restrict__ y, const float* __restrict__ sb)
{
    size_t start = (size_t)blockIdx.x * blockDim.x + threadIdx.x;
    int c0 = (int)((start * 4) & (COUT - 1));   // invariant under grid stride
    float sc[4], bi[4];
#pragma unroll
    for (int j = 0; j < 4; ++j) { sc[j] = sb[c0 + j]; bi[j] = sb[COUT + c0 + j]; }

    const size_t total = (size_t)NPTS * COUT / 4;
    const size_t step  = (size_t)gridDim.x * blockDim.x;
    for (size_t idx = start; idx < total; idx += step) {
        float4 v = ((const float4*)y)[idx];
        v.x = v.x * sc[0] + bi[0]; v.x = v.x > 0.f ? v.x : NEG_SLOPE * v.x;
        v.y = v.y * sc[1] + bi[1]; v.y = v.y > 0.f ? v.y : NEG_SLOPE * v.y;
        v.z = v.z * sc[2] + bi[2]; v.z = v.z > 0.f ? v.z : NEG_SLOPE * v.z;
        v.w = v.w * sc[3] + bi[3]; v.w = v.w > 0.f ? v.w : NEG_SLOPE * v.w;
        ((float4*)y)[idx] = v;
    }
}

extern "C" void kernel_launch(void* const* d_in, const int* in_sizes, int n_in,
                              void* d_out, int out_size, void* d_ws, size_t ws_size,
                              hipStream_t stream)
{
    const float* feats = (const float*)d_in[0];
    const int*   nidx  = (const int*)d_in[1];
    const int*   nmask = (const int*)d_in[2];
    const float* W     = (const float*)d_in[3];
    const float* gamma = (const float*)d_in[4];
    const float* beta  = (const float*)d_in[5];

    float* y = (float*)d_out;

    // ws layout
    float*          accum  = (float*)d_ws;                               // 1 KB
    float*          sb     = (float*)((char*)d_ws + 1024);               // 1 KB
    unsigned short* Wt     = (unsigned short*)((char*)d_ws + 4096);      // 442 KB
    unsigned short* featsb = (unsigned short*)((char*)d_ws + 458752);    // 16.78 MB (NPTS+1 rows)
    int*            midx   = (int*)((char*)d_ws + 17236224);             // 14.16 MB
    const size_t need_midx = 17236224 + (size_t)NPTS * K * sizeof(int);
    const bool use_midx = ws_size >= need_midx;

    hipMemsetAsync(accum, 0, 2 * COUT * sizeof(float), stream);
    hipMemsetAsync(featsb + (size_t)NPTS * CIN, 0, CIN * 2, stream);   // zero sentinel row

    prep_w<<<(K * COUT * CIN + 255) / 256, 256, 0, stream>>>(W, Wt);
    prep_f<<<(NPTS * CIN / 8) / 256, 256, 0, stream>>>(feats, featsb);
    if (use_midx) {
        prep_idx<<<(NPTS * K + 255) / 256, 256, 0, stream>>>(nidx, nmask, midx);
        conv_kernel<true><<<NPTS / BM, 256, 0, stream>>>(featsb, midx, nidx, nmask, Wt, y, accum);
    } else {
        conv_kernel<false><<<NPTS / BM, 256, 0, stream>>>(featsb, midx, nidx, nmask, Wt, y, accum);
    }
    finalize_kernel<<<1, 128, 0, stream>>>(accum, gamma, beta, sb);
    bn_kernel<<<2048, 256, 0, stream>>>(y, sb);
}

// Round 10
// 121.846 us; speedup vs baseline: 1.4274x; 1.4274x over previous
//
#include <hip/hip_runtime.h>
#include <hip/hip_bf16.h>

#define NPTS 131072
#define K 27
#define CIN 64
#define COUT 128
#define BM 128                // rows per conv block (8 waves: 4r x 2c)

constexpr float BN_EPS = 1e-5f;
constexpr float NEG_SLOPE = 0.01f;

typedef __attribute__((ext_vector_type(8))) short short8;
typedef __attribute__((ext_vector_type(4))) float f32x4;

__device__ inline unsigned int pk_bf16(float a, float b) {
    __hip_bfloat16 ha = __float2bfloat16(a), hb = __float2bfloat16(b);
    unsigned short ua = *reinterpret_cast<unsigned short*>(&ha);
    unsigned short ub = *reinterpret_cast<unsigned short*>(&hb);
    return (unsigned int)ua | ((unsigned int)ub << 16);
}
__device__ inline unsigned short bf16_bits(float a) {
    __hip_bfloat16 h = __float2bfloat16(a);
    return *reinterpret_cast<unsigned short*>(&h);
}

// ---------------------------------------------------------------------------
// prep_all: fused prep_f + prep_w + prep_idx (one launch).
//   t in [0, 1048576): feats f32 -> featsb bf16 (32 B per thread)
//   t < 221184:        W -> Wt [27][128][64] bf16
//   t < 884736:        (nidx, nmask) -> midx int4 (sentinel NPTS)
// ---------------------------------------------------------------------------
__global__ __launch_bounds__(256) void prep_all(
    const float* __restrict__ feats, const float* __restrict__ W,
    const int* __restrict__ nidx, const int* __restrict__ nmask,
    unsigned short* __restrict__ featsb, unsigned short* __restrict__ Wt,
    int* __restrict__ midx, int do_midx)
{
    size_t t = (size_t)blockIdx.x * 256 + threadIdx.x;   // 4096 blocks

    // feats -> bf16
    {
        const float4* src = (const float4*)(feats) + t * 2;
        float4 v0 = src[0], v1 = src[1];
        uint4 o;
        o.x = pk_bf16(v0.x, v0.y); o.y = pk_bf16(v0.z, v0.w);
        o.z = pk_bf16(v1.x, v1.y); o.w = pk_bf16(v1.z, v1.w);
        ((uint4*)featsb)[t] = o;
    }
    // W -> Wt (transposed)
    if (t < (size_t)K * COUT * CIN) {
        int k  = (int)(t / (COUT * CIN));
        int r  = (int)(t % (COUT * CIN));
        int co = r / CIN;
        int ci = r % CIN;
        Wt[t] = bf16_bits(W[(k * CIN + ci) * COUT + co]);
    }
    // mask fold -> midx (int4)
    if (do_midx && t < (size_t)(NPTS * K / 4)) {
        int4 iv = ((const int4*)nidx)[t];
        int4 mv = ((const int4*)nmask)[t];
        int4 o;
        o.x = mv.x ? iv.x : NPTS;
        o.y = mv.y ? iv.y : NPTS;
        o.z = mv.z ? iv.z : NPTS;
        o.w = mv.w ? iv.w : NPTS;
        ((int4*)midx)[t] = o;
    }
}

// ---------------------------------------------------------------------------
// conv: R5-proven structure at BM=128.  512 thr = 8 waves (4r x 2c),
// 128x128 out tile.  Reg-staged gather -> XOR-swizzled LDS, 1-deep
// prefetch, 2 barriers/k.  B traffic per output HALVED vs BM=64; 27K
// block-iters chip-wide (was 55K); 32 KB LDS -> 4 resident blocks/CU.
// ---------------------------------------------------------------------------
template<bool MIDX, bool YB>
__global__ __launch_bounds__(512) void conv_kernel(
    const unsigned short* __restrict__ featsb,   // (NPTS+1) rows, last = 0
    const int* __restrict__ midx,                // if MIDX
    const int* __restrict__ nidx,                // else
    const int* __restrict__ nmask,
    const unsigned short* __restrict__ Wt,       // [27][128][64] bf16
    float* __restrict__ y,                       // if !YB
    unsigned short* __restrict__ ybf,            // if YB
    float* __restrict__ accum)                   // [256]: sums then sumsqs
{
    __shared__ unsigned char Alds[BM * 128];      // 16 KB
    __shared__ unsigned char Blds[COUT * 128];    // 16 KB

    const int tid  = threadIdx.x;
    const int l    = tid & 63;
    const int wid  = tid >> 6;        // 0..7
    const int wr   = wid >> 1;        // 0..3 (32 rows each)
    const int wc   = wid & 1;         // 0..1 (64 cols each)
    const int base = blockIdx.x * BM;

    const int arow = tid >> 2;        // 4 thr/row, 32 B each
    const int aq   = tid & 3;
    const int bcol = tid >> 2;        // 4 thr/col, 32 B each
    const int bq   = tid & 3;

    auto loadIdx = [&](int kq) -> int {
        kq = kq < K ? kq : K - 1;     // clamp (redundant, harmless)
        int o = (base + arow) * K + kq;
        if constexpr (MIDX) return midx[o];
        else                return nmask[o] ? nidx[o] : NPTS;
    };

    const int aswz = (arow & 7) << 4;
    unsigned char* ap = Alds + arow * 128;
    const int bswz = (bcol & 7) << 4;
    unsigned char* bp = Blds + bcol * 128;

    uint4 a0, a1, b0, b1;             // staged regs (32 B A, 32 B B)
    int   id_nxt;

#define ISSUE_A(id)                                                           \
    { const uint4* p_ = (const uint4*)(featsb + (size_t)(id) * CIN) + aq * 2; \
      a0 = p_[0]; a1 = p_[1]; }
#define ISSUE_B(kq)                                                           \
    { const uint4* p_ = (const uint4*)(Wt + ((size_t)(kq) * COUT + bcol) * CIN) + bq * 2; \
      b0 = p_[0]; b1 = p_[1]; }
#define WRITE_AB()                                                            \
    { *(uint4*)(ap + ((aq * 32 +  0) ^ aswz)) = a0;                           \
      *(uint4*)(ap + ((aq * 32 + 16) ^ aswz)) = a1;                           \
      *(uint4*)(bp + ((bq * 32 +  0) ^ bswz)) = b0;                           \
      *(uint4*)(bp + ((bq * 32 + 16) ^ bswz)) = b1; }

    f32x4 acc[2][4];
#pragma unroll
    for (int m = 0; m < 2; ++m)
#pragma unroll
        for (int n = 0; n < 4; ++n) acc[m][n] = (f32x4)0.f;

#define MFMA_TILE()                                                           \
    _Pragma("unroll")                                                         \
    for (int ks = 0; ks < 2; ++ks) {                                          \
        const int kbyte = ks * 64 + (l >> 4) * 16;                            \
        short8 afr[2], bfr[4];                                                \
        _Pragma("unroll")                                                     \
        for (int m = 0; m < 2; ++m) {                                         \
            int row = wr * 32 + m * 16 + (l & 15);                            \
            afr[m] = *(const short8*)(Alds + row * 128                        \
                        + (kbyte ^ ((row & 7) << 4)));                        \
        }                                                                     \
        _Pragma("unroll")                                                     \
        for (int n = 0; n < 4; ++n) {                                         \
            int col = wc * 64 + n * 16 + (l & 15);                            \
            bfr[n] = *(const short8*)(Blds + col * 128                        \
                        + (kbyte ^ ((col & 7) << 4)));                        \
        }                                                                     \
        _Pragma("unroll")                                                     \
        for (int m = 0; m < 2; ++m)                                           \
            _Pragma("unroll")                                                 \
            for (int n = 0; n < 4; ++n)                                       \
                acc[m][n] = __builtin_amdgcn_mfma_f32_16x16x32_bf16(          \
                    afr[m], bfr[n], acc[m][n], 0, 0, 0);                      \
    }

    // ---- prologue: k=0 staged, id for k=1 prefetched ----
    {
        int id0 = loadIdx(0);
        ISSUE_A(id0);
        ISSUE_B(0);
        id_nxt = loadIdx(1);
    }

    // ---- main loop: 2 barriers per k ----
    for (int k = 0; k < K; ++k) {
        __syncthreads();              // waves done reading tile k-1
        WRITE_AB();
        if (k + 1 < K) {
            ISSUE_A(id_nxt);          // flies during MFMA k
            ISSUE_B(k + 1);
            id_nxt = loadIdx(k + 2);
        }
        __syncthreads();              // tile k visible
        MFMA_TILE();
    }

    // ---- y write: C/D layout col=l&15, row=(l>>4)*4+r ----
#pragma unroll
    for (int m = 0; m < 2; ++m)
#pragma unroll
        for (int n = 0; n < 4; ++n) {
            int gcol = wc * 64 + n * 16 + (l & 15);
#pragma unroll
            for (int r = 0; r < 4; ++r) {
                int grow = base + wr * 32 + m * 16 + (l >> 4) * 4 + r;
                if constexpr (YB) {
                    __builtin_nontemporal_store(bf16_bits(acc[m][n][r]),
                        &ybf[(size_t)grow * COUT + gcol]);
                } else {
                    __builtin_nontemporal_store(acc[m][n][r],
                        &y[(size_t)grow * COUT + gcol]);
                }
            }
        }

    // ---- fused per-block BN stats (exact f32, from acc regs) ----
    float sv[4], s2v[4];
#pragma unroll
    for (int n = 0; n < 4; ++n) {
        float s = 0.f, s2 = 0.f;
#pragma unroll
        for (int m = 0; m < 2; ++m)
#pragma unroll
            for (int r = 0; r < 4; ++r) { float v = acc[m][n][r]; s += v; s2 += v * v; }
        s  += __shfl_xor(s, 16);  s  += __shfl_xor(s, 32);
        s2 += __shfl_xor(s2, 16); s2 += __shfl_xor(s2, 32);
        sv[n] = s; s2v[n] = s2;
    }
    __syncthreads();                  // all MFMA reads of Alds done
    float* statf = (float*)Alds;      // [2][4][128] f32 = 4 KB
    if (l < 16) {
#pragma unroll
        for (int n = 0; n < 4; ++n) {
            int c = wc * 64 + n * 16 + l;
            statf[(0 * 4 + wr) * 128 + c] = sv[n];
            statf[(1 * 4 + wr) * 128 + c] = s2v[n];
        }
    }
    __syncthreads();
    if (tid < 128) {
        float s  = statf[0 * 128 + tid] + statf[1 * 128 + tid]
                 + statf[2 * 128 + tid] + statf[3 * 128 + tid];
        float s2 = statf[4 * 128 + tid] + statf[5 * 128 + tid]
                 + statf[6 * 128 + tid] + statf[7 * 128 + tid];
        atomicAdd(&accum[tid], s);
        atomicAdd(&accum[128 + tid], s2);
    }
#undef ISSUE_A
#undef ISSUE_B
#undef WRITE_AB
#undef MFMA_TILE
}

// ---------------------------------------------------------------------------
// finalize: fold mean/var/gamma/beta into per-channel scale+bias
// ---------------------------------------------------------------------------
__global__ void finalize_kernel(const float* __restrict__ accum,
                                const float* __restrict__ gamma,
                                const float* __restrict__ beta,
                                float* __restrict__ sb)
{
    int c = threadIdx.x;                      // 128 threads
    float invN  = 1.0f / (float)NPTS;
    float mean  = accum[c] * invN;
    float var   = accum[128 + c] * invN - mean * mean;
    float scale = gamma[c] * rsqrtf(var + BN_EPS);
    sb[c]       = scale;
    sb[128 + c] = beta[c] - mean * scale;
}

// ---------------------------------------------------------------------------
// bn: out = leaky(y*scale+bias).  YB: read bf16 y (8 ch / thread, uint4).
// ---------------------------------------------------------------------------
template<bool YB>
__global__ __launch_bounds__(256) void bn_kernel(
    const unsigned short* __restrict__ ybf, float* __restrict__ y,
    const float* __restrict__ sb)
{
    size_t start = (size_t)blockIdx.x * blockDim.x + threadIdx.x;
    const size_t step = (size_t)gridDim.x * blockDim.x;
    if constexpr (YB) {
        int c0 = (int)((start * 8) & (COUT - 1));   // grid-stride invariant
        float sc[8], bi[8];
#pragma unroll
        for (int j = 0; j < 8; ++j) { sc[j] = sb[c0 + j]; bi[j] = sb[COUT + c0 + j]; }
        const size_t total = (size_t)NPTS * COUT / 8;
        for (size_t idx = start; idx < total; idx += step) {
            uint4 u = ((const uint4*)ybf)[idx];
            unsigned int uu[4] = {u.x, u.y, u.z, u.w};
            float o[8];
#pragma unroll
            for (int j = 0; j < 4; ++j) {
                float vlo = __uint_as_float(uu[j] << 16);
                float vhi = __uint_as_float(uu[j] & 0xffff0000u);
                float a = vlo * sc[2*j]   + bi[2*j];
                float b = vhi * sc[2*j+1] + bi[2*j+1];
                o[2*j]   = a > 0.f ? a : NEG_SLOPE * a;
                o[2*j+1] = b > 0.f ? b : NEG_SLOPE * b;
            }
            float4* dst = (float4*)(y + idx * 8);
            dst[0] = make_float4(o[0], o[1], o[2], o[3]);
            dst[1] = make_float4(o[4], o[5], o[6], o[7]);
        }
    } else {
        int c0 = (int)((start * 4) & (COUT - 1));
        float sc[4], bi[4];
#pragma unroll
        for (int j = 0; j < 4; ++j) { sc[j] = sb[c0 + j]; bi[j] = sb[COUT + c0 + j]; }
        const size_t total = (size_t)NPTS * COUT / 4;
        for (size_t idx = start; idx < total; idx += step) {
            float4 v = ((const float4*)y)[idx];
            v.x = v.x * sc[0] + bi[0]; v.x = v.x > 0.f ? v.x : NEG_SLOPE * v.x;
            v.y = v.y * sc[1] + bi[1]; v.y = v.y > 0.f ? v.y : NEG_SLOPE * v.y;
            v.z = v.z * sc[2] + bi[2]; v.z = v.z > 0.f ? v.z : NEG_SLOPE * v.z;
            v.w = v.w * sc[3] + bi[3]; v.w = v.w > 0.f ? v.w : NEG_SLOPE * v.w;
            ((float4*)y)[idx] = v;
        }
    }
}

extern "C" void kernel_launch(void* const* d_in, const int* in_sizes, int n_in,
                              void* d_out, int out_size, void* d_ws, size_t ws_size,
                              hipStream_t stream)
{
    const float* feats = (const float*)d_in[0];
    const int*   nidx  = (const int*)d_in[1];
    const int*   nmask = (const int*)d_in[2];
    const float* W     = (const float*)d_in[3];
    const float* gamma = (const float*)d_in[4];
    const float* beta  = (const float*)d_in[5];

    float* y = (float*)d_out;

    // ws layout (byte offsets)
    float*          accum  = (float*)d_ws;                               // 1 KB
    float*          sb     = (float*)((char*)d_ws + 1024);               // 1 KB
    unsigned short* Wt     = (unsigned short*)((char*)d_ws + 4096);      // 442 KB
    unsigned short* featsb = (unsigned short*)((char*)d_ws + 458752);    // 16.78 MB
    int*            midx   = (int*)((char*)d_ws + 17236224);             // 14.16 MB
    unsigned short* ybf    = (unsigned short*)((char*)d_ws + 31494144);  // 33.55 MB
    const size_t need_midx = 31494144;
    const size_t need_ybf  = 31494144 + (size_t)NPTS * COUT * 2;
    const bool use_midx = ws_size >= need_midx;
    const bool use_ybf  = ws_size >= need_ybf;

    hipMemsetAsync(accum, 0, 2 * COUT * sizeof(float), stream);
    hipMemsetAsync(featsb + (size_t)NPTS * CIN, 0, CIN * 2, stream);   // sentinel

    prep_all<<<4096, 256, 0, stream>>>(feats, W, nidx, nmask,
                                       featsb, Wt, midx, (int)use_midx);

    if (use_midx && use_ybf)
        conv_kernel<true, true ><<<NPTS / BM, 512, 0, stream>>>(featsb, midx, nidx, nmask, Wt, y, ybf, accum);
    else if (use_midx)
        conv_kernel<true, false><<<NPTS / BM, 512, 0, stream>>>(featsb, midx, nidx, nmask, Wt, y, ybf, accum);
    else
        conv_kernel<false, false><<<NPTS / BM, 512, 0, stream>>>(featsb, midx, nidx, nmask, Wt, y, ybf, accum);

    finalize_kernel<<<1, 128, 0, stream>>>(accum, gamma, beta, sb);

    if (use_midx && use_ybf)
        bn_kernel<true ><<<2048, 256, 0, stream>>>(ybf, y, sb);
    else
        bn_kernel<false><<<2048, 256, 0, stream>>>(ybf, y, sb);
}